// Round 11
// baseline (1117.971 us; speedup 1.0000x reference)
//
#include <hip/hip_runtime.h>
#include <stdint.h>

// SemsegCDRLink R10b: resubmit of R10 (previous run died to infra, not the
// kernel). Barrier-free conv. B fragments read DIRECTLY from global
// frag-order W (L2-resident, 0.5MB/layer) -> no LDS staging, no per-tap
// __syncthreads; waves fully async. Keeps: XCD-chunked swizzle, col-split
// l1/l3, exec-masked gathers, idx prefetch, fused BN stats.

constexpr int NPT = 200000;   // N voxels
constexpr int KNB = 27;       // kernel taps

typedef unsigned short u16;
typedef __attribute__((ext_vector_type(8))) short     bf16x8;
typedef __attribute__((ext_vector_type(8))) unsigned short u16x8;
typedef __attribute__((ext_vector_type(4))) float     f32x4;

static __device__ __forceinline__ u16 f2bf(float f){
  unsigned int u = __float_as_uint(f);
  unsigned int r = (u + 0x7fffu + ((u >> 16) & 1u)) >> 16;
  return (u16)r;
}
static __device__ __forceinline__ float bf2f(u16 u){
  return __uint_as_float(((unsigned int)u) << 16);
}

// ---------------------------------------------------------------- mask dtype
// numpy bool arrives as uint8 or int32; both little-endian 0/1 => LSB byte at
// scaled offset works for both: byte index = o << (fInt ? 2 : 0).
__global__ void detect_mask_kernel(const int* __restrict__ m32, int* __restrict__ flag){
  if (threadIdx.x == 0 && blockIdx.x == 0){
    int ok = 1;
    for (int i = 0; i < 64; ++i){ int v = m32[i]; if (v != 0 && v != 1) ok = 0; }
    *flag = ok ? 2 : 0;   // byte-offset shift: 2 => int32 masks, 0 => uint8
  }
}

// ------------------------------------------------- feat_2d transpose to NHWC
__global__ __launch_bounds__(256) void transpose2d_kernel(const float* __restrict__ in,
                                                          u16* __restrict__ out){
  __shared__ float tile[64][33];
  int bid = blockIdx.x;
  int wt = bid % 5;  int rest = bid / 5;
  int h  = rest % 120; rest /= 120;
  int b  = rest % 4;  int v = rest / 4;
  int w0 = wt * 32;
  int tx = threadIdx.x & 31;
  int ty = threadIdx.x >> 5;
  const float* ip = in + ((size_t)(v*4 + b) * 64) * 19200 + h * 160 + w0;
  #pragma unroll
  for (int cc = 0; cc < 8; ++cc){
    int c = cc * 8 + ty;
    tile[c][tx] = ip[(size_t)c * 19200 + tx];
  }
  __syncthreads();
  u16* op = out + (((size_t)(v*4 + b) * 120 + h) * 160 + w0) * 64;
  int c = threadIdx.x & 63;
  int wg = threadIdx.x >> 6;
  #pragma unroll
  for (int i = 0; i < 8; ++i){
    int w = wg + i * 4;
    op[(size_t)w * 64 + c] = f2bf(tile[c][w]);
  }
}

// ------------------------------------------------------------ weight reshape
// src: [K][cin][coutF] f32 -> frag order for 16x16x32 over a coutT-col slice:
// dst[((k*NKC+kc)*NCB+cb)*512 + lane*8 + e] =
//   W[k][kc*32+(lane>>4)*8+e][cbase + cb*16 + (lane&15)]
__global__ void wconvert_kernel(const float* __restrict__ src, u16* __restrict__ dst,
                                int cin, int coutT, int coutF, int cbase){
  int gid = blockIdx.x * 256 + threadIdx.x;
  int tot = KNB * cin * coutT;
  if (gid >= tot) return;
  int ncb = coutT / 16;
  int nkc = cin / 32;
  int e    = gid & 7;
  int lane = (gid >> 3) & 63;
  int f    = gid >> 9;
  int cb   = f % ncb;  f /= ncb;
  int kc   = f % nkc;
  int k    = f / nkc;
  int ci = kc * 32 + (lane >> 4) * 8 + e;
  int co = cbase + cb * 16 + (lane & 15);
  dst[gid] = f2bf(src[((size_t)k * cin + ci) * coutF + co]);
}

// --------------------------------------------------------------- 2D->3D gather
__global__ void stage_a_kernel(const u16* __restrict__ ft, const int* __restrict__ links,
                               const int* __restrict__ cmi, const int* __restrict__ cmo,
                               u16* __restrict__ x0){
  int gid = blockIdx.x * 256 + threadIdx.x;
  if (gid >= NPT * 3) return;
  int i = gid / 3;
  int v = gid - i * 3;
  int outr = cmo[i];
  int l    = cmi[i];
  int b  = links[l*12 + v];
  int h  = links[l*12 + 3 + v];
  int w  = links[l*12 + 6 + v];
  int vl = links[l*12 + 9 + v];
  u16* dst = x0 + (size_t)outr * 192 + v * 64;
  if (vl){
    const u16* src = ft + (((size_t)(v*4 + b) * 120 + h) * 160 + w) * 64;
    #pragma unroll
    for (int j = 0; j < 8; ++j) ((u16x8*)dst)[j] = ((const u16x8*)src)[j];
  } else {
    u16x8 z = {};
    #pragma unroll
    for (int j = 0; j < 8; ++j) ((u16x8*)dst)[j] = z;
  }
}

// --------------------------------- feat3d f32 -> X3 cols [0,96) (stride 192)
__global__ void f3convert_kernel(const float* __restrict__ src, u16* __restrict__ dst){
  long gid = (long)blockIdx.x * 256 + threadIdx.x;
  long tot8 = (long)NPT * 12;           // 96/8 groups per row
  if (gid >= tot8) return;
  int row = (int)(gid / 12);
  int c0  = (int)(gid % 12) * 8;
  const float* s = src + (size_t)row * 96 + c0;
  u16* d = dst + (size_t)row * 192 + c0;
  #pragma unroll
  for (int j = 0; j < 8; ++j) d[j] = f2bf(s[j]);
}

// ------------------------------------------------------------------ conv core
// 256 thr = 4 waves, 128 rows/block (32 rows/wave = 2x 16-row MFMA tiles).
// NO LDS staging, NO per-tap barriers: B fragments read directly from the
// frag-order WT array (L2-resident; contiguous 1KB per wave-instr). Waves
// run fully async across the 27-tap loop. XCD-chunked swizzle; COLSPLIT:
// v&1 selects col slice. Exec-masked gathers; idx/mask prefetch 1 tap ahead.
template<int CIN, int COUT_T, bool COLSPLIT, bool F32OUT>
__global__ __launch_bounds__(256)
void conv_kernel(const u16* __restrict__ x0,
                 const u16* __restrict__ wtA, const u16* __restrict__ wtB,
                 const int* __restrict__ in_idx,
                 const uint8_t* __restrict__ mbytes,
                 const int* __restrict__ flagp, void* __restrict__ outp,
                 int outStride, float* __restrict__ st, int nwork){
  constexpr int NCB    = COUT_T / 16;
  constexpr int NKC    = CIN / 32;
  constexpr int COUTF  = COLSPLIT ? COUT_T * 2 : COUT_T;
  __shared__ float shS[COUT_T], shQ[COUT_T];

  // XCD-chunked virtual work id (hardware round-robins bid%8 across XCDs)
  const int v = (blockIdx.x & 7) * (gridDim.x >> 3) + (blockIdx.x >> 3);
  if (v >= nwork) return;

  const int tid    = threadIdx.x;
  const int lane   = tid & 63;
  const int wv     = tid >> 6;
  const int r16    = lane & 15;
  const int kgrp   = lane >> 4;
  const int half   = COLSPLIT ? (v & 1) : 0;
  const int m0     = (COLSPLIT ? (v >> 1) : v) * 128;
  const int cbase  = half * COUT_T;
  const u16* wt    = (COLSPLIT && half) ? wtB : wtA;
  const int mshift = *flagp;                    // 0 (u8) or 2 (i32)

  if (tid < COUT_T){ shS[tid] = 0.f; shQ[tid] = 0.f; }

  f32x4 acc[2][NCB];
  #pragma unroll
  for (int rt = 0; rt < 2; ++rt)
    #pragma unroll
    for (int cb = 0; cb < NCB; ++cb) acc[rt][cb] = (f32x4)0.0f;

  int rowc[2];
  #pragma unroll
  for (int rt = 0; rt < 2; ++rt){
    int row = m0 + wv * 32 + rt * 16 + r16;
    rowc[rt] = row < NPT ? row : NPT - 1;
  }

  int idC[2]; bool mC[2];
  #pragma unroll
  for (int rt = 0; rt < 2; ++rt){
    idC[rt] = in_idx[rowc[rt]];
    mC[rt]  = mbytes[(size_t)rowc[rt] << mshift] != 0;
  }

  const u16* xk = x0 + kgrp * 8;             // fold kgrp offset into base
  const u16* wl = wt + (size_t)lane * 8;     // fold lane offset into W base

  for (int k = 0; k < KNB; ++k){
    // gather A[k], exec-masked: invalid lanes issue no requests, frag = 0
    bf16x8 a0[NKC], a1[NKC];
    #pragma unroll
    for (int kc = 0; kc < NKC; ++kc){ bf16x8 z = {}; a0[kc] = z; a1[kc] = z; }
    if (mC[0]){
      const u16* b0 = xk + (size_t)idC[0] * CIN;
      #pragma unroll
      for (int kc = 0; kc < NKC; ++kc) a0[kc] = *(const bf16x8*)(b0 + kc * 32);
    }
    if (mC[1]){
      const u16* b1 = xk + (size_t)idC[1] * CIN;
      #pragma unroll
      for (int kc = 0; kc < NKC; ++kc) a1[kc] = *(const bf16x8*)(b1 + kc * 32);
    }

    // prefetch idx/mask[k+1]
    if (k + 1 < KNB){
      #pragma unroll
      for (int rt = 0; rt < 2; ++rt){
        size_t o = (size_t)(k + 1) * NPT + rowc[rt];
        idC[rt] = in_idx[o];
        mC[rt]  = mbytes[o << mshift] != 0;
      }
    }

    // MFMAs: B direct from global frag-order W (L2-hit, coalesced 1KB/instr)
    const u16* wk = wl + (size_t)k * (NKC * NCB * 512);
    #pragma unroll
    for (int kc = 0; kc < NKC; ++kc){
      #pragma unroll
      for (int cb = 0; cb < NCB; ++cb){
        bf16x8 b = *(const bf16x8*)(wk + (kc * NCB + cb) * 512);
        acc[0][cb] = __builtin_amdgcn_mfma_f32_16x16x32_bf16(a0[kc], b, acc[0][cb], 0, 0, 0);
        acc[1][cb] = __builtin_amdgcn_mfma_f32_16x16x32_bf16(a1[kc], b, acc[1][cb], 0, 0, 0);
      }
    }
  }

  // epilogue: C/D col = lane&15, row = kgrp*4 + j  [m89-verified]
  __syncthreads();   // shS/shQ zero-init visible
  #pragma unroll
  for (int rt = 0; rt < 2; ++rt){
    #pragma unroll
    for (int cb = 0; cb < NCB; ++cb){
      const int cout = cb * 16 + r16;
      float s = 0.f, q = 0.f;
      #pragma unroll
      for (int j = 0; j < 4; ++j){
        int row = m0 + wv * 32 + rt * 16 + kgrp * 4 + j;
        if (row < NPT){
          float v2 = acc[rt][cb][j];
          if (F32OUT) ((float*)outp)[(size_t)row * outStride + cbase + cout] = v2;
          else        ((u16*)outp)[(size_t)row * outStride + cbase + cout] = f2bf(v2);
          s += v2; q += v2 * v2;
        }
      }
      atomicAdd(&shS[cout], s); atomicAdd(&shQ[cout], q);
    }
  }
  __syncthreads();
  if (tid < COUT_T){
    atomicAdd(&st[cbase + tid],         shS[tid]);
    atomicAdd(&st[COUTF + cbase + tid], shQ[tid]);
  }
}

// --------------------------------------------------------------- BN + ReLU
template<int CCH, bool ISF32>
__global__ void bnrelu_kernel(void* __restrict__ xp, int stride,
                              const float* __restrict__ st,
                              const float* __restrict__ gg, const float* __restrict__ bb){
  const float invN = 1.0f / (float)NPT;
  constexpr int GPR = CCH / 8;
  long tot8 = (long)NPT * GPR;
  for (long e8 = (long)blockIdx.x * 256 + threadIdx.x; e8 < tot8; e8 += (long)gridDim.x * 256){
    int row = (int)(e8 / GPR);
    int c0  = (int)(e8 % GPR) * 8;
    size_t base = (size_t)row * stride + c0;
    #pragma unroll
    for (int j = 0; j < 8; ++j){
      int c = c0 + j;
      float mu  = st[c] * invN;
      float var = st[CCH + c] * invN - mu * mu;
      float rs  = rsqrtf(var + 1e-5f);
      float x;
      if (ISF32) x = ((float*)xp)[base + j];
      else       x = bf2f(((u16*)xp)[base + j]);
      float y = gg[c] * (x - mu) * rs + bb[c];
      y = y > 0.f ? y : 0.f;
      if (ISF32) ((float*)xp)[base + j] = y;
      else       ((u16*)xp)[base + j] = f2bf(y);
    }
  }
}

// =====================================================================
extern "C" void kernel_launch(void* const* d_in, const int* in_sizes, int n_in,
                              void* d_out, int out_size, void* d_ws, size_t ws_size,
                              hipStream_t stream){
  const float* feat2d = (const float*)d_in[0];
  const float* feat3d = (const float*)d_in[1];
  const int*   links  = (const int*)d_in[2];
  const int*   cmi    = (const int*)d_in[3];
  const int*   cmo    = (const int*)d_in[4];
  const int*   inidx  = (const int*)d_in[5];
  const void*  mask   = d_in[6];
  const float* W1 = (const float*)d_in[7];
  const float* g1 = (const float*)d_in[8];
  const float* b1 = (const float*)d_in[9];
  const float* W2 = (const float*)d_in[10];
  const float* g2 = (const float*)d_in[11];
  const float* b2 = (const float*)d_in[12];
  const float* W3 = (const float*)d_in[13];
  const float* g3 = (const float*)d_in[14];
  const float* b3 = (const float*)d_in[15];

  // ws layout (bytes), high-water ~108.3 MB:
  //  [0, 76.80M)           X0 (N,192)bf16 ; reused as X3=[F3|H2] (N,192)
  //  [76.80M, 106.29M)     FT (29.5M) ; after stage_a reused as Z1 (N,64)
  //  [106.29M, 108.28M)    W frag-order slices (1.99MB)
  //  [108.28M, ...)        stats (512 f32) + flag
  char* ws = (char*)d_ws;
  u16* X0 = (u16*)(ws + 0);                    // also X3
  constexpr size_t OFF_B  = 76800512;
  u16* FT = (u16*)(ws + OFF_B);
  u16* Z1 = (u16*)(ws + OFF_B);
  u16* WT1a = (u16*)(ws + 106291712);          // 27*192*32 = 165888 elems
  u16* WT1b = WT1a + 27 * 192 * 32;            // 165888
  u16* WT2  = WT1b + 27 * 192 * 32;            // 27*64*96 = 165888
  u16* WT3a = WT2  + 27 * 64 * 96;             // 27*192*48 = 248832
  u16* WT3b = WT3a + 27 * 192 * 48;            // 248832
  float* ST  = (float*)(ws + 108282368);
  float* ST1 = ST;            // 128 floats (S|Q)
  float* ST2 = ST + 128;      // 192 floats
  float* ST3 = ST + 320;      // 192 floats
  int*   FLAG = (int*)(ST + 512);

  hipMemsetAsync(ST, 0, 513 * sizeof(float), stream);
  detect_mask_kernel<<<1, 64, 0, stream>>>((const int*)mask, FLAG);
  transpose2d_kernel<<<7200, 256, 0, stream>>>(feat2d, FT);
  wconvert_kernel<<<(27*192*32 + 255)/256, 256, 0, stream>>>(W1, WT1a, 192, 32, 64, 0);
  wconvert_kernel<<<(27*192*32 + 255)/256, 256, 0, stream>>>(W1, WT1b, 192, 32, 64, 32);
  wconvert_kernel<<<(27*64*96  + 255)/256, 256, 0, stream>>>(W2, WT2, 64, 96, 96, 0);
  wconvert_kernel<<<(27*192*48 + 255)/256, 256, 0, stream>>>(W3, WT3a, 192, 48, 96, 0);
  wconvert_kernel<<<(27*192*48 + 255)/256, 256, 0, stream>>>(W3, WT3b, 192, 48, 96, 48);
  stage_a_kernel<<<(NPT*3 + 255)/256, 256, 0, stream>>>(FT, links, cmi, cmo, X0);

  const int nblk = (NPT + 127) / 128;          // 1563
  const int nsplit = 2 * nblk;                 // 3126
  const int gsplit = ((nsplit + 7) / 8) * 8;   // 3128 (2 idle blocks)
  const int gnorm  = ((nblk + 7) / 8) * 8;     // 1568 (5 idle blocks)
  const uint8_t* m8 = (const uint8_t*)mask;

  // layer 1 (col-split 32+32): X0 (N,192) -> Z1 (N,64)   [Z1 overwrites FT]
  conv_kernel<192, 32, true, false><<<gsplit, 256, 0, stream>>>(
      X0, WT1a, WT1b, inidx, m8, FLAG, Z1, 64, ST1, nsplit);
  bnrelu_kernel<64, false><<<2048, 256, 0, stream>>>(Z1, 64, ST1, g1, b1);

  // build X3: cols [0,96) = bf16(feat3d)      [overwrites X0 after conv1]
  f3convert_kernel<<<((NPT*12) + 255)/256, 256, 0, stream>>>(feat3d, X0);

  // layer 2: Z1 (N,64) -> X3 cols [96,192)
  conv_kernel<64, 96, false, false><<<gnorm, 256, 0, stream>>>(
      Z1, WT2, nullptr, inidx, m8, FLAG, X0 + 96, 192, ST2, nblk);
  bnrelu_kernel<96, false><<<2048, 256, 0, stream>>>(X0 + 96, 192, ST2, g2, b2);

  // layer 3 (col-split 48+48): X3 (N,192) -> d_out (N,96) f32
  conv_kernel<192, 48, true, true><<<gsplit, 256, 0, stream>>>(
      X0, WT3a, WT3b, inidx, m8, FLAG, d_out, 96, ST3, nsplit);
  bnrelu_kernel<96, true><<<2048, 256, 0, stream>>>(d_out, 96, ST3, g3, b3);
}

// Round 12
// 1034.001 us; speedup vs baseline: 1.0812x; 1.0812x over previous
//
#include <hip/hip_runtime.h>
#include <stdint.h>

// SemsegCDRLink R12: amortization round. NT=4 row-tiles per wave (64 rows/
// wave, 256 rows/block) -> per-tap overhead (barrier, idx loads, stage,
// B-LDS traffic) amortized over 2x the MFMA work. All three layers
// col-split (acc<=48 regs, LDS dbuf<=37KB). Sentinel-row gathers (branch-
// free). W dbuf in LDS via global_load_lds, ONE barrier/tap. XCD swizzle.

constexpr int NPT = 200000;   // N voxels
constexpr int KNB = 27;       // kernel taps

typedef unsigned short u16;
typedef __attribute__((ext_vector_type(8))) short     bf16x8;
typedef __attribute__((ext_vector_type(8))) unsigned short u16x8;
typedef __attribute__((ext_vector_type(4))) float     f32x4;

static __device__ __forceinline__ u16 f2bf(float f){
  unsigned int u = __float_as_uint(f);
  unsigned int r = (u + 0x7fffu + ((u >> 16) & 1u)) >> 16;
  return (u16)r;
}
static __device__ __forceinline__ float bf2f(u16 u){
  return __uint_as_float(((unsigned int)u) << 16);
}

// global -> LDS direct copy, 16B per lane; lds dest is wave-uniform base.
static __device__ __forceinline__ void gload_lds16(const void* g, void* l){
  __builtin_amdgcn_global_load_lds(
      (const __attribute__((address_space(1))) void*)g,
      (__attribute__((address_space(3))) void*)(uint32_t)(uintptr_t)l,
      16, 0, 0);
}

// ---------------------------------------------------------------- mask dtype
// numpy bool arrives as uint8 or int32; both little-endian 0/1 => LSB byte at
// scaled offset works for both: byte index = o << (fInt ? 2 : 0).
__global__ void detect_mask_kernel(const int* __restrict__ m32, int* __restrict__ flag){
  if (threadIdx.x == 0 && blockIdx.x == 0){
    int ok = 1;
    for (int i = 0; i < 64; ++i){ int v = m32[i]; if (v != 0 && v != 1) ok = 0; }
    *flag = ok ? 2 : 0;   // byte-offset shift: 2 => int32 masks, 0 => uint8
  }
}

// ------------------------------------------------- feat_2d transpose to NHWC
__global__ __launch_bounds__(256) void transpose2d_kernel(const float* __restrict__ in,
                                                          u16* __restrict__ out){
  __shared__ float tile[64][33];
  int bid = blockIdx.x;
  int wt = bid % 5;  int rest = bid / 5;
  int h  = rest % 120; rest /= 120;
  int b  = rest % 4;  int v = rest / 4;
  int w0 = wt * 32;
  int tx = threadIdx.x & 31;
  int ty = threadIdx.x >> 5;
  const float* ip = in + ((size_t)(v*4 + b) * 64) * 19200 + h * 160 + w0;
  #pragma unroll
  for (int cc = 0; cc < 8; ++cc){
    int c = cc * 8 + ty;
    tile[c][tx] = ip[(size_t)c * 19200 + tx];
  }
  __syncthreads();
  u16* op = out + (((size_t)(v*4 + b) * 120 + h) * 160 + w0) * 64;
  int c = threadIdx.x & 63;
  int wg = threadIdx.x >> 6;
  #pragma unroll
  for (int i = 0; i < 8; ++i){
    int w = wg + i * 4;
    op[(size_t)w * 64 + c] = f2bf(tile[c][w]);
  }
}

// ------------------------------------------------------------ weight reshape
// src: [K][cin][coutF] f32 -> frag order for 16x16x32 over a coutT-col slice:
// dst[((k*NKC+kc)*NCB+cb)*512 + lane*8 + e] =
//   W[k][kc*32+(lane>>4)*8+e][cbase + cb*16 + (lane&15)]
__global__ void wconvert_kernel(const float* __restrict__ src, u16* __restrict__ dst,
                                int cin, int coutT, int coutF, int cbase){
  int gid = blockIdx.x * 256 + threadIdx.x;
  int tot = KNB * cin * coutT;
  if (gid >= tot) return;
  int ncb = coutT / 16;
  int nkc = cin / 32;
  int e    = gid & 7;
  int lane = (gid >> 3) & 63;
  int f    = gid >> 9;
  int cb   = f % ncb;  f /= ncb;
  int kc   = f % nkc;
  int k    = f / nkc;
  int ci = kc * 32 + (lane >> 4) * 8 + e;
  int co = cbase + cb * 16 + (lane & 15);
  dst[gid] = f2bf(src[((size_t)k * cin + ci) * coutF + co]);
}

// --------------------------------------------------------------- 2D->3D gather
__global__ void stage_a_kernel(const u16* __restrict__ ft, const int* __restrict__ links,
                               const int* __restrict__ cmi, const int* __restrict__ cmo,
                               u16* __restrict__ x0){
  int gid = blockIdx.x * 256 + threadIdx.x;
  if (gid >= NPT * 3) return;
  int i = gid / 3;
  int v = gid - i * 3;
  int outr = cmo[i];
  int l    = cmi[i];
  int b  = links[l*12 + v];
  int h  = links[l*12 + 3 + v];
  int w  = links[l*12 + 6 + v];
  int vl = links[l*12 + 9 + v];
  u16* dst = x0 + (size_t)outr * 192 + v * 64;
  if (vl){
    const u16* src = ft + (((size_t)(v*4 + b) * 120 + h) * 160 + w) * 64;
    #pragma unroll
    for (int j = 0; j < 8; ++j) ((u16x8*)dst)[j] = ((const u16x8*)src)[j];
  } else {
    u16x8 z = {};
    #pragma unroll
    for (int j = 0; j < 8; ++j) ((u16x8*)dst)[j] = z;
  }
}

// --------------------------------- feat3d f32 -> X3 cols [0,96) (stride 192)
__global__ void f3convert_kernel(const float* __restrict__ src, u16* __restrict__ dst){
  long gid = (long)blockIdx.x * 256 + threadIdx.x;
  long tot8 = (long)NPT * 12;           // 96/8 groups per row
  if (gid >= tot8) return;
  int row = (int)(gid / 12);
  int c0  = (int)(gid % 12) * 8;
  const float* s = src + (size_t)row * 96 + c0;
  u16* d = dst + (size_t)row * 192 + c0;
  #pragma unroll
  for (int j = 0; j < 8; ++j) d[j] = f2bf(s[j]);
}

// ------------------------------------------------------------------ conv core
// 256 thr = 4 waves; NT row-tiles of 16 rows per wave => 64*NT rows/block.
// Sentinel gathers: vidx = mask ? idx : NPT (row NPT zeroed; branch-free).
// W dbuf in LDS via global_load_lds; stage W[k+1] issued at TOP of tap k;
// ONE __syncthreads per tap (drains vmcnt -> publishes W[k+1]). All layers
// col-split: v&1 selects slice. XCD-chunked swizzle. Fused BN stats.
template<int CIN, int COUT_T, int NT, bool F32OUT>
__global__ __launch_bounds__(256)
void conv_kernel(const u16* __restrict__ x0,
                 const u16* __restrict__ wtA, const u16* __restrict__ wtB,
                 const int* __restrict__ in_idx,
                 const uint8_t* __restrict__ mbytes,
                 const int* __restrict__ flagp, void* __restrict__ outp,
                 int outStride, float* __restrict__ st, int nwork){
  constexpr int NCB    = COUT_T / 16;
  constexpr int NKC    = CIN / 32;
  constexpr int WELE   = CIN * COUT_T;          // u16 elems per tap
  constexpr int NCHUNK = (WELE * 2) / 1024;     // 1KB chunks per tap
  constexpr int ROUNDS = (NCHUNK + 3) / 4;
  constexpr int COUTF  = COUT_T * 2;            // full layer width
  constexpr int RPB    = 64 * NT;               // rows per block
  __shared__ __align__(16) u16 wlds[2 * WELE];
  __shared__ float shS[COUT_T], shQ[COUT_T];

  // XCD-chunked virtual work id (hardware round-robins bid%8 across XCDs)
  const int v = (blockIdx.x & 7) * (gridDim.x >> 3) + (blockIdx.x >> 3);
  if (v >= nwork) return;

  const int tid    = threadIdx.x;
  const int lane   = tid & 63;
  const int wv     = tid >> 6;
  const int r16    = lane & 15;
  const int kgrp   = lane >> 4;
  const int half   = v & 1;
  const int m0     = (v >> 1) * RPB;
  const int cbase  = half * COUT_T;
  const u16* wt    = half ? wtB : wtA;
  const int mshift = *flagp;                    // 0 (u8) or 2 (i32)

  if (tid < COUT_T){ shS[tid] = 0.f; shQ[tid] = 0.f; }

  f32x4 acc[NT][NCB];
  #pragma unroll
  for (int rt = 0; rt < NT; ++rt)
    #pragma unroll
    for (int cb = 0; cb < NCB; ++cb) acc[rt][cb] = (f32x4)0.0f;

  int rowc[NT];
  #pragma unroll
  for (int rt = 0; rt < NT; ++rt){
    int row = m0 + wv * (16 * NT) + rt * 16 + r16;
    rowc[rt] = row < NPT ? row : NPT - 1;
  }

  // prologue: stage W[0] -> buf0, load sentinel-fused vidx[0]
  #pragma unroll
  for (int rd = 0; rd < ROUNDS; ++rd){
    int chunk = rd * 4 + wv;
    if (chunk < NCHUNK)
      gload_lds16((const char*)wt + chunk * 1024 + lane * 16,
                  (char*)wlds + chunk * 1024);
  }
  int vC[NT];
  #pragma unroll
  for (int rt = 0; rt < NT; ++rt){
    int id = in_idx[rowc[rt]];
    int mv = mbytes[(size_t)rowc[rt] << mshift];
    vC[rt] = mv ? id : NPT;
  }
  __syncthreads();                           // publishes W[0]

  const u16* xk = x0 + kgrp * 8;             // fold kgrp offset into base

  for (int k = 0; k < KNB; ++k){
    // stage W[k+1] -> other buffer, issued EARLY (hidden under this tap's
    // compute; that buffer's last readers finished at the previous barrier)
    if (k + 1 < KNB){
      const u16* wn = wt + (size_t)(k + 1) * WELE;
      char* wd = (char*)wlds + ((k + 1) & 1) * (WELE * 2);
      #pragma unroll
      for (int rd = 0; rd < ROUNDS; ++rd){
        int chunk = rd * 4 + wv;
        if (chunk < NCHUNK)
          gload_lds16((const char*)wn + chunk * 1024 + lane * 16,
                      wd + chunk * 1024);
      }
    }

    // gather bases for tap k (sentinel: invalid rows read zeroed row NPT)
    const u16* gb[NT];
    #pragma unroll
    for (int rt = 0; rt < NT; ++rt) gb[rt] = xk + (size_t)vC[rt] * CIN;

    // prefetch sentinel-fused vidx[k+1]
    if (k + 1 < KNB){
      #pragma unroll
      for (int rt = 0; rt < NT; ++rt){
        size_t o = (size_t)(k + 1) * NPT + rowc[rt];
        int id = in_idx[o];
        int mv = mbytes[o << mshift];
        vC[rt] = mv ? id : NPT;
      }
    }

    // kc-outer: gather NT fragments, then NCB x NT MFMAs (B frag shared)
    const u16* wb = &wlds[(k & 1) * WELE];
    #pragma unroll
    for (int kc = 0; kc < NKC; ++kc){
      bf16x8 a[NT];
      #pragma unroll
      for (int rt = 0; rt < NT; ++rt)
        a[rt] = *(const bf16x8*)(gb[rt] + kc * 32);
      #pragma unroll
      for (int cb = 0; cb < NCB; ++cb){
        bf16x8 b = *(const bf16x8*)&wb[((kc * NCB + cb) * 64 + lane) * 8];
        #pragma unroll
        for (int rt = 0; rt < NT; ++rt)
          acc[rt][cb] = __builtin_amdgcn_mfma_f32_16x16x32_bf16(a[rt], b, acc[rt][cb], 0, 0, 0);
      }
    }
    __syncthreads();       // end of tap: drains vmcnt -> publishes W[k+1]
  }

  // epilogue: C/D col = lane&15, row = kgrp*4 + j  [m89-verified]
  #pragma unroll
  for (int rt = 0; rt < NT; ++rt){
    #pragma unroll
    for (int cb = 0; cb < NCB; ++cb){
      const int cout = cb * 16 + r16;
      float s = 0.f, q = 0.f;
      #pragma unroll
      for (int j = 0; j < 4; ++j){
        int row = m0 + wv * (16 * NT) + rt * 16 + kgrp * 4 + j;
        if (row < NPT){
          float v2 = acc[rt][cb][j];
          if (F32OUT) ((float*)outp)[(size_t)row * outStride + cbase + cout] = v2;
          else        ((u16*)outp)[(size_t)row * outStride + cbase + cout] = f2bf(v2);
          s += v2; q += v2 * v2;
        }
      }
      atomicAdd(&shS[cout], s); atomicAdd(&shQ[cout], q);
    }
  }
  __syncthreads();
  if (tid < COUT_T){
    atomicAdd(&st[cbase + tid],         shS[tid]);
    atomicAdd(&st[COUTF + cbase + tid], shQ[tid]);
  }
}

// --------------------------------------------------------------- BN + ReLU
template<int CCH, bool ISF32>
__global__ void bnrelu_kernel(void* __restrict__ xp, int stride,
                              const float* __restrict__ st,
                              const float* __restrict__ gg, const float* __restrict__ bb){
  const float invN = 1.0f / (float)NPT;
  constexpr int GPR = CCH / 8;
  long tot8 = (long)NPT * GPR;
  for (long e8 = (long)blockIdx.x * 256 + threadIdx.x; e8 < tot8; e8 += (long)gridDim.x * 256){
    int row = (int)(e8 / GPR);
    int c0  = (int)(e8 % GPR) * 8;
    size_t base = (size_t)row * stride + c0;
    #pragma unroll
    for (int j = 0; j < 8; ++j){
      int c = c0 + j;
      float mu  = st[c] * invN;
      float var = st[CCH + c] * invN - mu * mu;
      float rs  = rsqrtf(var + 1e-5f);
      float x;
      if (ISF32) x = ((float*)xp)[base + j];
      else       x = bf2f(((u16*)xp)[base + j]);
      float y = gg[c] * (x - mu) * rs + bb[c];
      y = y > 0.f ? y : 0.f;
      if (ISF32) ((float*)xp)[base + j] = y;
      else       ((u16*)xp)[base + j] = f2bf(y);
    }
  }
}

// =====================================================================
extern "C" void kernel_launch(void* const* d_in, const int* in_sizes, int n_in,
                              void* d_out, int out_size, void* d_ws, size_t ws_size,
                              hipStream_t stream){
  const float* feat2d = (const float*)d_in[0];
  const float* feat3d = (const float*)d_in[1];
  const int*   links  = (const int*)d_in[2];
  const int*   cmi    = (const int*)d_in[3];
  const int*   cmo    = (const int*)d_in[4];
  const int*   inidx  = (const int*)d_in[5];
  const void*  mask   = d_in[6];
  const float* W1 = (const float*)d_in[7];
  const float* g1 = (const float*)d_in[8];
  const float* b1 = (const float*)d_in[9];
  const float* W2 = (const float*)d_in[10];
  const float* g2 = (const float*)d_in[11];
  const float* b2 = (const float*)d_in[12];
  const float* W3 = (const float*)d_in[13];
  const float* g3 = (const float*)d_in[14];
  const float* b3 = (const float*)d_in[15];

  // ws layout (bytes), high-water ~108.3 MB:
  //  [0, 76.80M)           X0 (N+1,192)bf16 ; reused as X3=[F3|H2] (N+1,192)
  //  [76.80M, 106.29M)     FT (29.5M) ; after stage_a reused as Z1 (N+1,64)
  //  [106.29M, 108.28M)    W frag-order slices (1.99MB)
  //  [108.28M, ...)        stats (512 f32) + flag
  char* ws = (char*)d_ws;
  u16* X0 = (u16*)(ws + 0);                    // also X3
  constexpr size_t OFF_B  = 76800512;
  u16* FT = (u16*)(ws + OFF_B);
  u16* Z1 = (u16*)(ws + OFF_B);
  u16* WT1a = (u16*)(ws + 106291712);          // 27*192*32 = 165888 elems
  u16* WT1b = WT1a + 27 * 192 * 32;            // 165888
  u16* WT2a = WT1b + 27 * 192 * 32;            // 27*64*48 = 82944
  u16* WT2b = WT2a + 27 * 64 * 48;             // 82944
  u16* WT3a = WT2b + 27 * 64 * 48;             // 27*192*48 = 248832
  u16* WT3b = WT3a + 27 * 192 * 48;            // 248832
  float* ST  = (float*)(ws + 108282368);
  float* ST1 = ST;            // 128 floats (S|Q)
  float* ST2 = ST + 128;      // 192 floats
  float* ST3 = ST + 320;      // 192 floats
  int*   FLAG = (int*)(ST + 512);

  hipMemsetAsync(ST, 0, 513 * sizeof(float), stream);
  detect_mask_kernel<<<1, 64, 0, stream>>>((const int*)mask, FLAG);
  transpose2d_kernel<<<7200, 256, 0, stream>>>(feat2d, FT);
  wconvert_kernel<<<(27*192*32 + 255)/256, 256, 0, stream>>>(W1, WT1a, 192, 32, 64, 0);
  wconvert_kernel<<<(27*192*32 + 255)/256, 256, 0, stream>>>(W1, WT1b, 192, 32, 64, 32);
  wconvert_kernel<<<(27*64*48  + 255)/256, 256, 0, stream>>>(W2, WT2a, 64, 48, 96, 0);
  wconvert_kernel<<<(27*64*48  + 255)/256, 256, 0, stream>>>(W2, WT2b, 64, 48, 96, 48);
  wconvert_kernel<<<(27*192*48 + 255)/256, 256, 0, stream>>>(W3, WT3a, 192, 48, 96, 0);
  wconvert_kernel<<<(27*192*48 + 255)/256, 256, 0, stream>>>(W3, WT3b, 192, 48, 96, 48);
  stage_a_kernel<<<(NPT*3 + 255)/256, 256, 0, stream>>>(FT, links, cmi, cmo, X0);

  // Sentinel rows — AFTER stage_a (R4 lesson: earlier corrupts FT pixels).
  // X0/X3 row NPT (384B) and Z1 row NPT (128B); no kernel writes row NPT,
  // so sentinels persist across graph replays.
  hipMemsetAsync(ws + (size_t)NPT * 384, 0, 384, stream);
  hipMemsetAsync(ws + OFF_B + (size_t)NPT * 128, 0, 128, stream);

  // NT=4: 256 rows/block; col-split doubles work ids
  const int nblk   = (NPT + 255) / 256;        // 782
  const int nsplit = 2 * nblk;                 // 1564
  const int gsplit = ((nsplit + 7) / 8) * 8;   // 1568
  const uint8_t* m8 = (const uint8_t*)mask;

  // layer 1 (col-split 32+32): X0 (N,192) -> Z1 (N,64)   [Z1 overwrites FT]
  conv_kernel<192, 32, 4, false><<<gsplit, 256, 0, stream>>>(
      X0, WT1a, WT1b, inidx, m8, FLAG, Z1, 64, ST1, nsplit);
  bnrelu_kernel<64, false><<<2048, 256, 0, stream>>>(Z1, 64, ST1, g1, b1);

  // build X3: cols [0,96) = bf16(feat3d)      [overwrites X0 after conv1]
  f3convert_kernel<<<((NPT*12) + 255)/256, 256, 0, stream>>>(feat3d, X0);

  // layer 2 (col-split 48+48): Z1 (N,64) -> X3 cols [96,192)
  conv_kernel<64, 48, 4, false><<<gsplit, 256, 0, stream>>>(
      Z1, WT2a, WT2b, inidx, m8, FLAG, X0 + 96, 192, ST2, nsplit);
  bnrelu_kernel<96, false><<<2048, 256, 0, stream>>>(X0 + 96, 192, ST2, g2, b2);

  // layer 3 (col-split 48+48): X3 (N,192) -> d_out (N,96) f32
  conv_kernel<192, 48, 4, true><<<gsplit, 256, 0, stream>>>(
      X0, WT3a, WT3b, inidx, m8, FLAG, d_out, 96, ST3, nsplit);
  bnrelu_kernel<96, true><<<2048, 256, 0, stream>>>(d_out, 96, ST3, g3, b3);
}

// Round 14
// 816.373 us; speedup vs baseline: 1.3694x; 1.2666x over previous
//
#include <hip/hip_runtime.h>
#include <stdint.h>

// SemsegCDRLink R13b: resubmit of R13 (previous run died to infra, not the
// kernel). Kill col-split (it doubled gather line-traffic through the
// L1-miss path, the binding resource). Occupancy held instead by
// SINGLE-buffered W in LDS (2 barriers/tap, R5-proven loop shape):
// l1 24.6KB / l2 12.3KB / l3 36.9KB -> 4 blocks/CU. 16x16x32 MFMA,
// frag-order W via global_load_lds, sentinel gathers, XCD swizzle,
// fused BN stats.

constexpr int NPT = 200000;   // N voxels
constexpr int KNB = 27;       // kernel taps

typedef unsigned short u16;
typedef __attribute__((ext_vector_type(8))) short     bf16x8;
typedef __attribute__((ext_vector_type(8))) unsigned short u16x8;
typedef __attribute__((ext_vector_type(4))) float     f32x4;

static __device__ __forceinline__ u16 f2bf(float f){
  unsigned int u = __float_as_uint(f);
  unsigned int r = (u + 0x7fffu + ((u >> 16) & 1u)) >> 16;
  return (u16)r;
}
static __device__ __forceinline__ float bf2f(u16 u){
  return __uint_as_float(((unsigned int)u) << 16);
}

// global -> LDS direct copy, 16B per lane; lds dest is wave-uniform base.
static __device__ __forceinline__ void gload_lds16(const void* g, void* l){
  __builtin_amdgcn_global_load_lds(
      (const __attribute__((address_space(1))) void*)g,
      (__attribute__((address_space(3))) void*)(uint32_t)(uintptr_t)l,
      16, 0, 0);
}

// ---------------------------------------------------------------- mask dtype
// numpy bool arrives as uint8 or int32; both little-endian 0/1 => LSB byte at
// scaled offset works for both: byte index = o << (fInt ? 2 : 0).
__global__ void detect_mask_kernel(const int* __restrict__ m32, int* __restrict__ flag){
  if (threadIdx.x == 0 && blockIdx.x == 0){
    int ok = 1;
    for (int i = 0; i < 64; ++i){ int v = m32[i]; if (v != 0 && v != 1) ok = 0; }
    *flag = ok ? 2 : 0;   // byte-offset shift: 2 => int32 masks, 0 => uint8
  }
}

// ------------------------------------------------- feat_2d transpose to NHWC
__global__ __launch_bounds__(256) void transpose2d_kernel(const float* __restrict__ in,
                                                          u16* __restrict__ out){
  __shared__ float tile[64][33];
  int bid = blockIdx.x;
  int wt = bid % 5;  int rest = bid / 5;
  int h  = rest % 120; rest /= 120;
  int b  = rest % 4;  int v = rest / 4;
  int w0 = wt * 32;
  int tx = threadIdx.x & 31;
  int ty = threadIdx.x >> 5;
  const float* ip = in + ((size_t)(v*4 + b) * 64) * 19200 + h * 160 + w0;
  #pragma unroll
  for (int cc = 0; cc < 8; ++cc){
    int c = cc * 8 + ty;
    tile[c][tx] = ip[(size_t)c * 19200 + tx];
  }
  __syncthreads();
  u16* op = out + (((size_t)(v*4 + b) * 120 + h) * 160 + w0) * 64;
  int c = threadIdx.x & 63;
  int wg = threadIdx.x >> 6;
  #pragma unroll
  for (int i = 0; i < 8; ++i){
    int w = wg + i * 4;
    op[(size_t)w * 64 + c] = f2bf(tile[c][w]);
  }
}

// ------------------------------------------------------------ weight reshape
// src: [K][cin][cout] f32 -> frag order for 16x16x32:
// dst[((k*NKC+kc)*NCB+cb)*512 + lane*8 + e] =
//   W[k][kc*32+(lane>>4)*8+e][cb*16+(lane&15)]
__global__ void wconvert_kernel(const float* __restrict__ src, u16* __restrict__ dst,
                                int cin, int cout){
  int gid = blockIdx.x * 256 + threadIdx.x;
  int tot = KNB * cin * cout;
  if (gid >= tot) return;
  int ncb = cout / 16;
  int nkc = cin / 32;
  int e    = gid & 7;
  int lane = (gid >> 3) & 63;
  int f    = gid >> 9;
  int cb   = f % ncb;  f /= ncb;
  int kc   = f % nkc;
  int k    = f / nkc;
  int ci = kc * 32 + (lane >> 4) * 8 + e;
  int co = cb * 16 + (lane & 15);
  dst[gid] = f2bf(src[((size_t)k * cin + ci) * cout + co]);
}

// --------------------------------------------------------------- 2D->3D gather
__global__ void stage_a_kernel(const u16* __restrict__ ft, const int* __restrict__ links,
                               const int* __restrict__ cmi, const int* __restrict__ cmo,
                               u16* __restrict__ x0){
  int gid = blockIdx.x * 256 + threadIdx.x;
  if (gid >= NPT * 3) return;
  int i = gid / 3;
  int v = gid - i * 3;
  int outr = cmo[i];
  int l    = cmi[i];
  int b  = links[l*12 + v];
  int h  = links[l*12 + 3 + v];
  int w  = links[l*12 + 6 + v];
  int vl = links[l*12 + 9 + v];
  u16* dst = x0 + (size_t)outr * 192 + v * 64;
  if (vl){
    const u16* src = ft + (((size_t)(v*4 + b) * 120 + h) * 160 + w) * 64;
    #pragma unroll
    for (int j = 0; j < 8; ++j) ((u16x8*)dst)[j] = ((const u16x8*)src)[j];
  } else {
    u16x8 z = {};
    #pragma unroll
    for (int j = 0; j < 8; ++j) ((u16x8*)dst)[j] = z;
  }
}

// --------------------------------- feat3d f32 -> X3 cols [0,96) (stride 192)
__global__ void f3convert_kernel(const float* __restrict__ src, u16* __restrict__ dst){
  long gid = (long)blockIdx.x * 256 + threadIdx.x;
  long tot8 = (long)NPT * 12;           // 96/8 groups per row
  if (gid >= tot8) return;
  int row = (int)(gid / 12);
  int c0  = (int)(gid % 12) * 8;
  const float* s = src + (size_t)row * 96 + c0;
  u16* d = dst + (size_t)row * 192 + c0;
  #pragma unroll
  for (int j = 0; j < 8; ++j) d[j] = f2bf(s[j]);
}

// ------------------------------------------------------------------ conv core
// 256 thr = 4 waves, 128 rows/block (32 rows/wave = 2x 16-row MFMA tiles).
// Sentinel gathers: vidx = mask ? idx : NPT (row NPT zeroed; branch-free).
// W SINGLE-buffered in LDS (frag order): per tap {MFMAs -> barrier ->
// stage W[k+1] via global_load_lds -> barrier}. Small LDS keeps 4 blk/CU,
// which keeps the L1-miss path (the binding resource) at full concurrency.
// XCD-chunked swizzle. Fused BN stats.
template<int CIN, int COUT, bool F32OUT>
__global__ __launch_bounds__(256)
void conv_kernel(const u16* __restrict__ x0, const u16* __restrict__ wt,
                 const int* __restrict__ in_idx,
                 const uint8_t* __restrict__ mbytes,
                 const int* __restrict__ flagp, void* __restrict__ outp,
                 int outStride, float* __restrict__ st, int nwork){
  constexpr int NCB    = COUT / 16;
  constexpr int NKC    = CIN / 32;
  constexpr int WELE   = CIN * COUT;            // u16 elems per tap
  constexpr int NCHUNK = (WELE * 2) / 1024;     // 1KB chunks per tap
  constexpr int ROUNDS = (NCHUNK + 3) / 4;
  __shared__ __align__(16) u16 wlds[WELE];
  __shared__ float shS[COUT], shQ[COUT];

  // XCD-chunked virtual work id (hardware round-robins bid%8 across XCDs)
  const int v = (blockIdx.x & 7) * (gridDim.x >> 3) + (blockIdx.x >> 3);
  if (v >= nwork) return;

  const int tid    = threadIdx.x;
  const int lane   = tid & 63;
  const int wv     = tid >> 6;
  const int r16    = lane & 15;
  const int kgrp   = lane >> 4;
  const int m0     = v * 128;
  const int mshift = *flagp;                    // 0 (u8) or 2 (i32)

  if (tid < COUT){ shS[tid] = 0.f; shQ[tid] = 0.f; }

  f32x4 acc[2][NCB];
  #pragma unroll
  for (int rt = 0; rt < 2; ++rt)
    #pragma unroll
    for (int cb = 0; cb < NCB; ++cb) acc[rt][cb] = (f32x4)0.0f;

  int rowc[2];
  #pragma unroll
  for (int rt = 0; rt < 2; ++rt){
    int row = m0 + wv * 32 + rt * 16 + r16;
    rowc[rt] = row < NPT ? row : NPT - 1;
  }

  // prologue: stage W[0], load sentinel-fused vidx[0]
  #pragma unroll
  for (int rd = 0; rd < ROUNDS; ++rd){
    int chunk = rd * 4 + wv;
    if (chunk < NCHUNK)
      gload_lds16((const char*)wt + chunk * 1024 + lane * 16,
                  (char*)wlds + chunk * 1024);
  }
  int vC[2];
  #pragma unroll
  for (int rt = 0; rt < 2; ++rt){
    int id = in_idx[rowc[rt]];
    int mv = mbytes[(size_t)rowc[rt] << mshift];
    vC[rt] = mv ? id : NPT;
  }
  __syncthreads();                           // W[0] published

  const u16* xk = x0 + kgrp * 8;             // fold kgrp offset into base

  for (int k = 0; k < KNB; ++k){
    // gather bases for tap k (sentinel: invalid rows read zeroed row NPT)
    const u16* gb0 = xk + (size_t)vC[0] * CIN;
    const u16* gb1 = xk + (size_t)vC[1] * CIN;

    // prefetch sentinel-fused vidx[k+1]
    if (k + 1 < KNB){
      #pragma unroll
      for (int rt = 0; rt < 2; ++rt){
        size_t o = (size_t)(k + 1) * NPT + rowc[rt];
        int id = in_idx[o];
        int mv = mbytes[o << mshift];
        vC[rt] = mv ? id : NPT;
      }
    }

    // kc-outer: 2 gathers then NCB MFMAs (B frag shared across row-tiles)
    #pragma unroll
    for (int kc = 0; kc < NKC; ++kc){
      bf16x8 a0 = *(const bf16x8*)(gb0 + kc * 32);
      bf16x8 a1 = *(const bf16x8*)(gb1 + kc * 32);
      #pragma unroll
      for (int cb = 0; cb < NCB; ++cb){
        bf16x8 b = *(const bf16x8*)&wlds[((kc * NCB + cb) * 64 + lane) * 8];
        acc[0][cb] = __builtin_amdgcn_mfma_f32_16x16x32_bf16(a0, b, acc[0][cb], 0, 0, 0);
        acc[1][cb] = __builtin_amdgcn_mfma_f32_16x16x32_bf16(a1, b, acc[1][cb], 0, 0, 0);
      }
    }
    __syncthreads();                 // all wlds reads for tap k done

    if (k + 1 < KNB){
      const u16* wn = wt + (size_t)(k + 1) * WELE;
      #pragma unroll
      for (int rd = 0; rd < ROUNDS; ++rd){
        int chunk = rd * 4 + wv;
        if (chunk < NCHUNK)
          gload_lds16((const char*)wn + chunk * 1024 + lane * 16,
                      (char*)wlds + chunk * 1024);
      }
      __syncthreads();               // drains vmcnt -> W[k+1] published
    }
  }

  // epilogue: C/D col = lane&15, row = kgrp*4 + j  [m89-verified]
  #pragma unroll
  for (int rt = 0; rt < 2; ++rt){
    #pragma unroll
    for (int cb = 0; cb < NCB; ++cb){
      const int cout = cb * 16 + r16;
      float s = 0.f, q = 0.f;
      #pragma unroll
      for (int j = 0; j < 4; ++j){
        int row = m0 + wv * 32 + rt * 16 + kgrp * 4 + j;
        if (row < NPT){
          float v2 = acc[rt][cb][j];
          if (F32OUT) ((float*)outp)[(size_t)row * outStride + cout] = v2;
          else        ((u16*)outp)[(size_t)row * outStride + cout] = f2bf(v2);
          s += v2; q += v2 * v2;
        }
      }
      atomicAdd(&shS[cout], s); atomicAdd(&shQ[cout], q);
    }
  }
  __syncthreads();
  if (tid < COUT){
    atomicAdd(&st[tid],        shS[tid]);
    atomicAdd(&st[COUT + tid], shQ[tid]);
  }
}

// --------------------------------------------------------------- BN + ReLU
template<int CCH, bool ISF32>
__global__ void bnrelu_kernel(void* __restrict__ xp, int stride,
                              const float* __restrict__ st,
                              const float* __restrict__ gg, const float* __restrict__ bb){
  const float invN = 1.0f / (float)NPT;
  constexpr int GPR = CCH / 8;
  long tot8 = (long)NPT * GPR;
  for (long e8 = (long)blockIdx.x * 256 + threadIdx.x; e8 < tot8; e8 += (long)gridDim.x * 256){
    int row = (int)(e8 / GPR);
    int c0  = (int)(e8 % GPR) * 8;
    size_t base = (size_t)row * stride + c0;
    #pragma unroll
    for (int j = 0; j < 8; ++j){
      int c = c0 + j;
      float mu  = st[c] * invN;
      float var = st[CCH + c] * invN - mu * mu;
      float rs  = rsqrtf(var + 1e-5f);
      float x;
      if (ISF32) x = ((float*)xp)[base + j];
      else       x = bf2f(((u16*)xp)[base + j]);
      float y = gg[c] * (x - mu) * rs + bb[c];
      y = y > 0.f ? y : 0.f;
      if (ISF32) ((float*)xp)[base + j] = y;
      else       ((u16*)xp)[base + j] = f2bf(y);
    }
  }
}

// =====================================================================
extern "C" void kernel_launch(void* const* d_in, const int* in_sizes, int n_in,
                              void* d_out, int out_size, void* d_ws, size_t ws_size,
                              hipStream_t stream){
  const float* feat2d = (const float*)d_in[0];
  const float* feat3d = (const float*)d_in[1];
  const int*   links  = (const int*)d_in[2];
  const int*   cmi    = (const int*)d_in[3];
  const int*   cmo    = (const int*)d_in[4];
  const int*   inidx  = (const int*)d_in[5];
  const void*  mask   = d_in[6];
  const float* W1 = (const float*)d_in[7];
  const float* g1 = (const float*)d_in[8];
  const float* b1 = (const float*)d_in[9];
  const float* W2 = (const float*)d_in[10];
  const float* g2 = (const float*)d_in[11];
  const float* b2 = (const float*)d_in[12];
  const float* W3 = (const float*)d_in[13];
  const float* g3 = (const float*)d_in[14];
  const float* b3 = (const float*)d_in[15];

  // ws layout (bytes), high-water ~108.3 MB:
  //  [0, 76.80M)           X0 (N+1,192)bf16 ; reused as X3=[F3|H2] (N+1,192)
  //  [76.80M, 106.29M)     FT (29.5M) ; after stage_a reused as Z1 (N+1,64)
  //  [106.29M, 108.28M)    WT1|WT2|WT3 bf16 frag order (1.99MB)
  //  [108.28M, ...)        stats (512 f32) + flag
  char* ws = (char*)d_ws;
  u16* X0 = (u16*)(ws + 0);                    // also X3
  constexpr size_t OFF_B  = 76800512;
  u16* FT = (u16*)(ws + OFF_B);
  u16* Z1 = (u16*)(ws + OFF_B);
  u16* WT1 = (u16*)(ws + 106291712);           // 27*192*64 = 331776 elems
  u16* WT2 = WT1 + 27 * 192 * 64;              // 27*64*96  = 165888
  u16* WT3 = WT2 + 27 * 64 * 96;               // 27*192*96 = 497664
  float* ST  = (float*)(ws + 108282368);
  float* ST1 = ST;            // 128 floats (S|Q)
  float* ST2 = ST + 128;      // 192 floats
  float* ST3 = ST + 320;      // 192 floats
  int*   FLAG = (int*)(ST + 512);

  hipMemsetAsync(ST, 0, 513 * sizeof(float), stream);
  detect_mask_kernel<<<1, 64, 0, stream>>>((const int*)mask, FLAG);
  transpose2d_kernel<<<7200, 256, 0, stream>>>(feat2d, FT);
  wconvert_kernel<<<(27*192*64 + 255)/256, 256, 0, stream>>>(W1, WT1, 192, 64);
  wconvert_kernel<<<(27*64*96  + 255)/256, 256, 0, stream>>>(W2, WT2, 64, 96);
  wconvert_kernel<<<(27*192*96 + 255)/256, 256, 0, stream>>>(W3, WT3, 192, 96);
  stage_a_kernel<<<(NPT*3 + 255)/256, 256, 0, stream>>>(FT, links, cmi, cmo, X0);

  // Sentinel rows — AFTER stage_a (R4 lesson: earlier corrupts FT pixels).
  // X0/X3 row NPT (384B) and Z1 row NPT (128B); no kernel writes row NPT,
  // so sentinels persist across graph replays.
  hipMemsetAsync(ws + (size_t)NPT * 384, 0, 384, stream);
  hipMemsetAsync(ws + OFF_B + (size_t)NPT * 128, 0, 128, stream);

  const int nblk = (NPT + 127) / 128;          // 1563
  const int grid = ((nblk + 7) / 8) * 8;       // 1568 (5 idle blocks)
  const uint8_t* m8 = (const uint8_t*)mask;

  // layer 1: X0 (N,192) -> Z1 (N,64)          [Z1 overwrites FT]
  conv_kernel<192, 64, false><<<grid, 256, 0, stream>>>(
      X0, WT1, inidx, m8, FLAG, Z1, 64, ST1, nblk);
  bnrelu_kernel<64, false><<<2048, 256, 0, stream>>>(Z1, 64, ST1, g1, b1);

  // build X3: cols [0,96) = bf16(feat3d)      [overwrites X0 after conv1]
  f3convert_kernel<<<((NPT*12) + 255)/256, 256, 0, stream>>>(feat3d, X0);

  // layer 2: Z1 (N,64) -> X3 cols [96,192)
  conv_kernel<64, 96, false><<<grid, 256, 0, stream>>>(
      Z1, WT2, inidx, m8, FLAG, X0 + 96, 192, ST2, nblk);
  bnrelu_kernel<96, false><<<2048, 256, 0, stream>>>(X0 + 96, 192, ST2, g2, b2);

  // layer 3: X3 (N,192) -> d_out (N,96) f32
  conv_kernel<192, 96, true><<<grid, 256, 0, stream>>>(
      X0, WT3, inidx, m8, FLAG, d_out, 96, ST3, nblk);
  bnrelu_kernel<96, true><<<2048, 256, 0, stream>>>(d_out, 96, ST3, g3, b3);
}